// Round 1
// baseline (909.085 us; speedup 1.0000x reference)
//
#include <hip/hip_runtime.h>

typedef __bf16 bf16;
typedef __bf16 bf16x8 __attribute__((ext_vector_type(8)));
typedef float f32x4 __attribute__((ext_vector_type(4)));

#define GLP16(gp, lp) __builtin_amdgcn_global_load_lds( \
    (const __attribute__((address_space(1))) void*)(gp), \
    (__attribute__((address_space(3))) void*)(lp), 16, 0, 0)

__device__ __forceinline__ f32x4 mfma16(bf16x8 a, bf16x8 b, f32x4 c) {
    return __builtin_amdgcn_mfma_f32_16x16x32_bf16(a, b, c, 0, 0, 0);
}

// ---------------- RMSNorm: fp32 in -> bf16 out, row = 2048 ----------------
__global__ __launch_bounds__(256) void k_rmsnorm(const float* __restrict__ x,
        const float* __restrict__ w, bf16* __restrict__ out) {
    const int H = 2048;
    size_t row = blockIdx.x;
    const float* xr = x + row * H;
    int base = threadIdx.x * 8;
    float4 a = *(const float4*)(xr + base);
    float4 b = *(const float4*)(xr + base + 4);
    float ss = a.x*a.x + a.y*a.y + a.z*a.z + a.w*a.w
             + b.x*b.x + b.y*b.y + b.z*b.z + b.w*b.w;
#pragma unroll
    for (int m = 32; m > 0; m >>= 1) ss += __shfl_xor(ss, m);
    __shared__ float red[4];
    if ((threadIdx.x & 63) == 0) red[threadIdx.x >> 6] = ss;
    __syncthreads();
    float tot = red[0] + red[1] + red[2] + red[3];
    float rs = rsqrtf(tot * (1.0f / H) + 1e-5f);
    float4 wa = *(const float4*)(w + base);
    float4 wb = *(const float4*)(w + base + 4);
    bf16x8 ov;
    ov[0] = (bf16)(a.x * rs * wa.x); ov[1] = (bf16)(a.y * rs * wa.y);
    ov[2] = (bf16)(a.z * rs * wa.z); ov[3] = (bf16)(a.w * rs * wa.w);
    ov[4] = (bf16)(b.x * rs * wb.x); ov[5] = (bf16)(b.y * rs * wb.y);
    ov[6] = (bf16)(b.z * rs * wb.z); ov[7] = (bf16)(b.w * rs * wb.w);
    *(bf16x8*)(out + row * H + base) = ov;
}

// ------- convert + transpose: W (K x N fp32) -> Wt (N x K bf16) -----------
__global__ __launch_bounds__(256) void k_convT(const float* __restrict__ W,
        bf16* __restrict__ Wt, int K, int N) {
    __shared__ float t[32][33];
    int k0 = blockIdx.x * 32, n0 = blockIdx.y * 32;
    int tx = threadIdx.x, ty = threadIdx.y;
#pragma unroll
    for (int i = 0; i < 4; i++)
        t[ty + i * 8][tx] = W[(size_t)(k0 + ty + i * 8) * N + n0 + tx];
    __syncthreads();
#pragma unroll
    for (int i = 0; i < 4; i++)
        Wt[(size_t)(n0 + ty + i * 8) * K + k0 + tx] = (bf16)t[tx][ty + i * 8];
}

// ---------------- GEMM: C[M][N] = A[M][K] * Bt[N][K]^T --------------------
// 128x128 tile, 4 waves (2x2 of 64x64), BK=32, mfma 16x16x32 bf16.
// EPI: 0 = store bf16, 1 = fp32 resid add, 2 = silu(gate)*acc -> bf16
template<int EPI>
__global__ __launch_bounds__(256) void k_gemm(const bf16* __restrict__ A,
        const bf16* __restrict__ Bt, void* __restrict__ outp,
        const void* __restrict__ aux, int M, int N, int K) {
    __shared__ bf16 As[128 * 32];
    __shared__ bf16 Bs[128 * 32];
    int tid = threadIdx.x;
    int wave = tid >> 6, lane = tid & 63;
    int lr = lane & 15, kg = lane >> 4;
    int bn = blockIdx.x, bm = blockIdx.y;
    int row0 = bm * 128, col0 = bn * 128;
    int wr = wave >> 1, wc = wave & 1;
    int ar = tid >> 2, ac = (tid & 3) * 8;
    const bf16* pa = A + (size_t)(row0 + ar) * K + ac;
    const bf16* pb = Bt + (size_t)(col0 + ar) * K + ac;
    char* lA = (char*)As + wave * 1024;
    char* lB = (char*)Bs + wave * 1024;
    f32x4 acc[4][4];
#pragma unroll
    for (int i = 0; i < 4; i++)
#pragma unroll
        for (int j = 0; j < 4; j++) acc[i][j] = (f32x4){0, 0, 0, 0};

    for (int k0 = 0; k0 < K; k0 += 32) {
        __syncthreads();
        GLP16(pa, lA);
        GLP16(pa + (size_t)64 * K, lA + 4096);
        GLP16(pb, lB);
        GLP16(pb + (size_t)64 * K, lB + 4096);
        pa += 32; pb += 32;
        __syncthreads();
        bf16x8 av[4], bv[4];
#pragma unroll
        for (int i = 0; i < 4; i++)
            av[i] = *(const bf16x8*)(As + (wr * 64 + i * 16 + lr) * 32 + kg * 8);
#pragma unroll
        for (int j = 0; j < 4; j++)
            bv[j] = *(const bf16x8*)(Bs + (wc * 64 + j * 16 + lr) * 32 + kg * 8);
#pragma unroll
        for (int i = 0; i < 4; i++)
#pragma unroll
            for (int j = 0; j < 4; j++)
                acc[i][j] = mfma16(av[i], bv[j], acc[i][j]);
    }
#pragma unroll
    for (int i = 0; i < 4; i++)
#pragma unroll
        for (int j = 0; j < 4; j++)
#pragma unroll
            for (int r = 0; r < 4; r++) {
                size_t row = row0 + wr * 64 + i * 16 + kg * 4 + r;
                size_t col = col0 + wc * 64 + j * 16 + lr;
                size_t idx = row * N + col;
                float vv = acc[i][j][r];
                if (EPI == 0) {
                    ((bf16*)outp)[idx] = (bf16)vv;
                } else if (EPI == 1) {
                    ((float*)outp)[idx] = ((const float*)aux)[idx] + vv;
                } else {
                    float g = (float)((const bf16*)aux)[idx];
                    float sg = g / (1.0f + __expf(-g));
                    ((bf16*)outp)[idx] = (bf16)(sg * vv);
                }
            }
}

// ------------- RoPE + qk-norm, in-place on q (S x 2048) / k (S x 512) -----
__global__ __launch_bounds__(64) void k_rope(bf16* __restrict__ q,
        bf16* __restrict__ k) {
    int s = blockIdx.x, hid = blockIdx.y, lane = threadIdx.x;
    bf16* p;
    if (hid < 16) p = q + (size_t)s * 2048 + hid * 128;
    else          p = k + (size_t)s * 512 + (hid - 16) * 128;
    float x1 = (float)p[lane], x2 = (float)p[lane + 64];
    float f = powf(10000.0f, -(float)lane * (1.0f / 64.0f));
    float sn, cs;
    sincosf((float)s * f, &sn, &cs);
    float o1 = x1 * cs - x2 * sn;
    float o2 = x2 * cs + x1 * sn;
    float ss = o1 * o1 + o2 * o2;
#pragma unroll
    for (int m = 32; m > 0; m >>= 1) ss += __shfl_xor(ss, m);
    float rs = rsqrtf(ss * (1.0f / 128.0f) + 1e-5f);
    p[lane] = (bf16)(o1 * rs);
    p[lane + 64] = (bf16)(o2 * rs);
}

// ------------- flash attention, GQA 16q/4kv, causal, tanh softcap ---------
// Block: 64 q-rows (4 waves x 16 rows), K/V tiles of 64. grid (S/64, NQ).
__global__ __launch_bounds__(256) void k_attn(const bf16* __restrict__ qg,
        const bf16* __restrict__ kgl, const bf16* __restrict__ vg,
        bf16* __restrict__ og) {
    __shared__ bf16 Qs[64 * 128];
    __shared__ bf16 Ks[64 * 128];
    __shared__ bf16 Vts[128 * 64];
    __shared__ bf16 Ps[64 * 64];
    int qb = blockIdx.x, h = blockIdx.y, kvh = h >> 2;
    int tid = threadIdx.x, wave = tid >> 6, lane = tid & 63;
    int lr = lane & 15, kgrp = lane >> 4;
    int sr = tid >> 4, sc = (tid & 15) * 8;
    const bf16* qp = qg + (size_t)(qb * 64 + sr) * 2048 + h * 128 + sc;
#pragma unroll
    for (int j = 0; j < 4; j++)
        GLP16(qp + (size_t)j * 16 * 2048, (char*)Qs + j * 4096 + wave * 1024);
    __syncthreads();
    bf16x8 qf[4];
#pragma unroll
    for (int c = 0; c < 4; c++)
        qf[c] = *(const bf16x8*)(Qs + (wave * 16 + lr) * 128 + c * 32 + kgrp * 8);
    f32x4 accO[8];
#pragma unroll
    for (int n = 0; n < 8; n++) accO[n] = (f32x4){0, 0, 0, 0};
    float lsum[4] = {0, 0, 0, 0};
    const float scl = 0.08838834764831845f;  // 1/sqrt(128)
    int ntiles = qb + 1;
    for (int kt = 0; kt < ntiles; kt++) {
        __syncthreads();
        const bf16* kp = kgl + (size_t)(kt * 64 + sr) * 512 + kvh * 128 + sc;
#pragma unroll
        for (int j = 0; j < 4; j++)
            GLP16(kp + (size_t)j * 16 * 512, (char*)Ks + j * 4096 + wave * 1024);
        const bf16* vp = vg + (size_t)(kt * 64 + sr) * 512 + kvh * 128 + sc;
#pragma unroll
        for (int j = 0; j < 4; j++) {
            bf16x8 vv = *(const bf16x8*)(vp + (size_t)j * 16 * 512);
            int r = sr + j * 16;
#pragma unroll
            for (int u = 0; u < 8; u++) Vts[(sc + u) * 64 + r] = vv[u];
        }
        __syncthreads();
        int qrow = qb * 64 + wave * 16 + kgrp * 4;
#pragma unroll
        for (int j = 0; j < 4; j++) {
            f32x4 s = {0, 0, 0, 0};
#pragma unroll
            for (int c = 0; c < 4; c++) {
                bf16x8 kf = *(const bf16x8*)(Ks + (j * 16 + lr) * 128 + c * 32 + kgrp * 8);
                s = mfma16(qf[c], kf, s);
            }
            int key = kt * 64 + j * 16 + lr;
#pragma unroll
            for (int r = 0; r < 4; r++) {
                float scv = 50.0f * tanhf(s[r] * scl * 0.02f);
                float pv = (key <= qrow + r) ? __expf(scv - 50.0f) : 0.0f;
                lsum[r] += pv;
                Ps[(wave * 16 + kgrp * 4 + r) * 64 + j * 16 + lr] = (bf16)pv;
            }
        }
        bf16x8 pf[2];
#pragma unroll
        for (int ks2 = 0; ks2 < 2; ks2++)
            pf[ks2] = *(const bf16x8*)(Ps + (wave * 16 + lr) * 64 + ks2 * 32 + kgrp * 8);
#pragma unroll
        for (int n = 0; n < 8; n++)
#pragma unroll
            for (int ks2 = 0; ks2 < 2; ks2++) {
                bf16x8 vf = *(const bf16x8*)(Vts + (n * 16 + lr) * 64 + ks2 * 32 + kgrp * 8);
                accO[n] = mfma16(pf[ks2], vf, accO[n]);
            }
    }
#pragma unroll
    for (int r = 0; r < 4; r++) {
        float t = lsum[r];
        t += __shfl_xor(t, 1); t += __shfl_xor(t, 2);
        t += __shfl_xor(t, 4); t += __shfl_xor(t, 8);
        lsum[r] = t;
    }
#pragma unroll
    for (int n = 0; n < 8; n++)
#pragma unroll
        for (int r = 0; r < 4; r++) {
            size_t row = qb * 64 + wave * 16 + kgrp * 4 + r;
            og[row * 2048 + h * 128 + n * 16 + lr] = (bf16)(accO[n][r] / lsum[r]);
        }
}

// --------------------------------------------------------------------------
extern "C" void kernel_launch(void* const* d_in, const int* in_sizes, int n_in,
                              void* d_out, int out_size, void* d_ws, size_t ws_size,
                              hipStream_t stream) {
    const float* x      = (const float*)d_in[0];
    const float* attn_w = (const float*)d_in[1];
    const float* mlp_w  = (const float*)d_in[2];
    const float* wq     = (const float*)d_in[3];
    const float* wk     = (const float*)d_in[4];
    const float* wv     = (const float*)d_in[5];
    const float* wo     = (const float*)d_in[6];
    const float* wgate  = (const float*)d_in[7];
    const float* wup    = (const float*)d_in[8];
    const float* wdown  = (const float*)d_in[9];
    float* out = (float*)d_out;
    char* ws = (char*)d_ws;

    const size_t MB = 1024 * 1024;
    bf16* W1  = (bf16*)(ws + 0);        // 32MB: wqT, later wgateT
    bf16* W2  = (bf16*)(ws + 32 * MB);  // 32MB: wkT, woT, wupT
    bf16* W3  = (bf16*)(ws + 64 * MB);  // 32MB: wvT, wdownT
    bf16* hb  = (bf16*)(ws + 96 * MB);  // 8MB: h, later h2
    bf16* qb  = (bf16*)(ws + 104 * MB); // 8MB
    bf16* kb  = (bf16*)(ws + 112 * MB); // 2MB
    bf16* vb  = (bf16*)(ws + 114 * MB); // 2MB
    bf16* ob  = (bf16*)(ws + 116 * MB); // 8MB
    float* x2 = (float*)(ws + 124 * MB);// 16MB
    bf16* gb  = (bf16*)(ws + 140 * MB); // 32MB (gate, then silu(g)*u in place)

    dim3 cb(32, 8);

    // 1. attn RMSNorm
    k_rmsnorm<<<2048, 256, 0, stream>>>(x, attn_w, hb);
    // 2. convert QKV weights (transposed bf16)
    k_convT<<<dim3(64, 64), cb, 0, stream>>>(wq, W1, 2048, 2048);
    k_convT<<<dim3(64, 16), cb, 0, stream>>>(wk, W2, 2048, 512);
    k_convT<<<dim3(64, 16), cb, 0, stream>>>(wv, W3, 2048, 512);
    // 3. QKV projections
    k_gemm<0><<<dim3(16, 16), 256, 0, stream>>>(hb, W1, qb, nullptr, 2048, 2048, 2048);
    k_gemm<0><<<dim3(4, 16), 256, 0, stream>>>(hb, W2, kb, nullptr, 2048, 512, 2048);
    k_gemm<0><<<dim3(4, 16), 256, 0, stream>>>(hb, W3, vb, nullptr, 2048, 512, 2048);
    // 4. RoPE + qk-norm (in place), q has 16 heads, k has 4
    k_rope<<<dim3(2048, 20), 64, 0, stream>>>(qb, kb);
    // 5. attention
    k_attn<<<dim3(32, 16), 256, 0, stream>>>(qb, kb, vb, ob);
    // 6. O projection + residual -> x2 (fp32)
    k_convT<<<dim3(64, 64), cb, 0, stream>>>(wo, W2, 2048, 2048);
    k_gemm<1><<<dim3(16, 16), 256, 0, stream>>>(ob, W2, x2, x, 2048, 2048, 2048);
    // 7. MLP RMSNorm
    k_rmsnorm<<<2048, 256, 0, stream>>>(x2, mlp_w, hb);
    // 8. gate GEMM
    k_convT<<<dim3(64, 256), cb, 0, stream>>>(wgate, W1, 2048, 8192);
    k_gemm<0><<<dim3(64, 16), 256, 0, stream>>>(hb, W1, gb, nullptr, 2048, 8192, 2048);
    // 9. up GEMM with silu(gate)*up epilogue (in place over gb)
    k_convT<<<dim3(64, 256), cb, 0, stream>>>(wup, W2, 2048, 8192);
    k_gemm<2><<<dim3(64, 16), 256, 0, stream>>>(hb, W2, gb, gb, 2048, 8192, 2048);
    // 10. down GEMM + residual -> out (fp32)
    k_convT<<<dim3(256, 64), cb, 0, stream>>>(wdown, W3, 8192, 2048);
    k_gemm<1><<<dim3(16, 16), 256, 0, stream>>>(gb, W3, out, x2, 2048, 2048, 8192);
}

// Round 2
// 770.617 us; speedup vs baseline: 1.1797x; 1.1797x over previous
//
#include <hip/hip_runtime.h>

typedef __bf16 bf16;
typedef __bf16 bf16x8 __attribute__((ext_vector_type(8)));
typedef float f32x4 __attribute__((ext_vector_type(4)));

#define GLP16(gp, lp) __builtin_amdgcn_global_load_lds( \
    (const __attribute__((address_space(1))) void*)(gp), \
    (__attribute__((address_space(3))) void*)(lp), 16, 0, 0)

__device__ __forceinline__ f32x4 mfma16(bf16x8 a, bf16x8 b, f32x4 c) {
    return __builtin_amdgcn_mfma_f32_16x16x32_bf16(a, b, c, 0, 0, 0);
}

// ---------------- RMSNorm: fp32 in -> bf16 out, row = 2048 ----------------
__global__ __launch_bounds__(256) void k_rmsnorm(const float* __restrict__ x,
        const float* __restrict__ w, bf16* __restrict__ out) {
    const int H = 2048;
    size_t row = blockIdx.x;
    const float* xr = x + row * H;
    int base = threadIdx.x * 8;
    float4 a = *(const float4*)(xr + base);
    float4 b = *(const float4*)(xr + base + 4);
    float ss = a.x*a.x + a.y*a.y + a.z*a.z + a.w*a.w
             + b.x*b.x + b.y*b.y + b.z*b.z + b.w*b.w;
#pragma unroll
    for (int m = 32; m > 0; m >>= 1) ss += __shfl_xor(ss, m);
    __shared__ float red[4];
    if ((threadIdx.x & 63) == 0) red[threadIdx.x >> 6] = ss;
    __syncthreads();
    float tot = red[0] + red[1] + red[2] + red[3];
    float rs = rsqrtf(tot * (1.0f / H) + 1e-5f);
    float4 wa = *(const float4*)(w + base);
    float4 wb = *(const float4*)(w + base + 4);
    bf16x8 ov;
    ov[0] = (bf16)(a.x * rs * wa.x); ov[1] = (bf16)(a.y * rs * wa.y);
    ov[2] = (bf16)(a.z * rs * wa.z); ov[3] = (bf16)(a.w * rs * wa.w);
    ov[4] = (bf16)(b.x * rs * wb.x); ov[5] = (bf16)(b.y * rs * wb.y);
    ov[6] = (bf16)(b.z * rs * wb.z); ov[7] = (bf16)(b.w * rs * wb.w);
    *(bf16x8*)(out + row * H + base) = ov;
}

// ------- convert + transpose: W (K x N fp32) -> Wt (N x K bf16) -----------
__global__ __launch_bounds__(256) void k_convT(const float* __restrict__ W,
        bf16* __restrict__ Wt, int K, int N) {
    __shared__ float t[32][33];
    int k0 = blockIdx.x * 32, n0 = blockIdx.y * 32;
    int tx = threadIdx.x, ty = threadIdx.y;
#pragma unroll
    for (int i = 0; i < 4; i++)
        t[ty + i * 8][tx] = W[(size_t)(k0 + ty + i * 8) * N + n0 + tx];
    __syncthreads();
#pragma unroll
    for (int i = 0; i < 4; i++)
        Wt[(size_t)(n0 + ty + i * 8) * K + k0 + tx] = (bf16)t[tx][ty + i * 8];
}

// ------- bf16 transpose: in (R x C) -> out (C x R) ------------------------
__global__ __launch_bounds__(256) void k_transpose(const bf16* __restrict__ in,
        bf16* __restrict__ out, int R, int C) {
    __shared__ bf16 t[32][33];
    int r0 = blockIdx.x * 32, c0 = blockIdx.y * 32;
    int tx = threadIdx.x & 31, ty = threadIdx.x >> 5;
#pragma unroll
    for (int i = 0; i < 4; i++)
        t[ty + i * 8][tx] = in[(size_t)(r0 + ty + i * 8) * C + c0 + tx];
    __syncthreads();
#pragma unroll
    for (int i = 0; i < 4; i++)
        out[(size_t)(c0 + ty + i * 8) * R + r0 + tx] = t[tx][ty + i * 8];
}

// ---------------- GEMM: C[M][N] = A[M][K] * Bt[N][K]^T --------------------
// 128x128 tile, 4 waves (2x2 of 64x64), BK=32, mfma 16x16x32 bf16.
// EPI: 0 = store bf16, 1 = fp32 resid add, 2 = silu(gate)*acc -> bf16
template<int EPI>
__global__ __launch_bounds__(256) void k_gemm(const bf16* __restrict__ A,
        const bf16* __restrict__ Bt, void* __restrict__ outp,
        const void* __restrict__ aux, int M, int N, int K) {
    __shared__ bf16 As[128 * 32];
    __shared__ bf16 Bs[128 * 32];
    int tid = threadIdx.x;
    int wave = tid >> 6, lane = tid & 63;
    int lr = lane & 15, kg = lane >> 4;
    int bn = blockIdx.x, bm = blockIdx.y;
    int row0 = bm * 128, col0 = bn * 128;
    int wr = wave >> 1, wc = wave & 1;
    int ar = tid >> 2, ac = (tid & 3) * 8;
    const bf16* pa = A + (size_t)(row0 + ar) * K + ac;
    const bf16* pb = Bt + (size_t)(col0 + ar) * K + ac;
    char* lA = (char*)As + wave * 1024;
    char* lB = (char*)Bs + wave * 1024;
    f32x4 acc[4][4];
#pragma unroll
    for (int i = 0; i < 4; i++)
#pragma unroll
        for (int j = 0; j < 4; j++) acc[i][j] = (f32x4){0, 0, 0, 0};

    for (int k0 = 0; k0 < K; k0 += 32) {
        __syncthreads();
        GLP16(pa, lA);
        GLP16(pa + (size_t)64 * K, lA + 4096);
        GLP16(pb, lB);
        GLP16(pb + (size_t)64 * K, lB + 4096);
        pa += 32; pb += 32;
        __syncthreads();
        bf16x8 av[4], bv[4];
#pragma unroll
        for (int i = 0; i < 4; i++)
            av[i] = *(const bf16x8*)(As + (wr * 64 + i * 16 + lr) * 32 + kg * 8);
#pragma unroll
        for (int j = 0; j < 4; j++)
            bv[j] = *(const bf16x8*)(Bs + (wc * 64 + j * 16 + lr) * 32 + kg * 8);
#pragma unroll
        for (int i = 0; i < 4; i++)
#pragma unroll
            for (int j = 0; j < 4; j++)
                acc[i][j] = mfma16(av[i], bv[j], acc[i][j]);
    }
#pragma unroll
    for (int i = 0; i < 4; i++)
#pragma unroll
        for (int j = 0; j < 4; j++)
#pragma unroll
            for (int r = 0; r < 4; r++) {
                size_t row = row0 + wr * 64 + i * 16 + kg * 4 + r;
                size_t col = col0 + wc * 64 + j * 16 + lr;
                size_t idx = row * N + col;
                float vv = acc[i][j][r];
                if (EPI == 0) {
                    ((bf16*)outp)[idx] = (bf16)vv;
                } else if (EPI == 1) {
                    ((float*)outp)[idx] = ((const float*)aux)[idx] + vv;
                } else {
                    float g = (float)((const bf16*)aux)[idx];
                    float sg = g / (1.0f + __expf(-g));
                    ((bf16*)outp)[idx] = (bf16)(sg * vv);
                }
            }
}

// ------------- RoPE + qk-norm, in-place on q (S x 2048) / k (S x 512) -----
__global__ __launch_bounds__(64) void k_rope(bf16* __restrict__ q,
        bf16* __restrict__ k) {
    int s = blockIdx.x, hid = blockIdx.y, lane = threadIdx.x;
    bf16* p;
    if (hid < 16) p = q + (size_t)s * 2048 + hid * 128;
    else          p = k + (size_t)s * 512 + (hid - 16) * 128;
    float x1 = (float)p[lane], x2 = (float)p[lane + 64];
    float f = powf(10000.0f, -(float)lane * (1.0f / 64.0f));
    float sn, cs;
    sincosf((float)s * f, &sn, &cs);
    float o1 = x1 * cs - x2 * sn;
    float o2 = x2 * cs + x1 * sn;
    float ss = o1 * o1 + o2 * o2;
#pragma unroll
    for (int m = 32; m > 0; m >>= 1) ss += __shfl_xor(ss, m);
    float rs = rsqrtf(ss * (1.0f / 128.0f) + 1e-5f);
    p[lane] = (bf16)(o1 * rs);
    p[lane + 64] = (bf16)(o2 * rs);
}

// ------------- flash attention, GQA 16q/4kv, causal, tanh softcap ---------
// Block: 64 q-rows (4 waves x 16 rows), K/V tiles of 64. grid (S/64, NQ).
// All LDS tiles XOR-swizzled (byte ^= (row&7)<<4); global_load_lds keeps a
// linear dest and the per-lane GLOBAL source is pre-swizzled (same involution).
// V consumed pre-transposed (vt[512][2048]).
__global__ __launch_bounds__(256) void k_attn(const bf16* __restrict__ qg,
        const bf16* __restrict__ kgl, const bf16* __restrict__ vtg,
        bf16* __restrict__ og) {
    __shared__ bf16 Qs[64 * 128];   // 256B rows, swizzled
    __shared__ bf16 Ks[64 * 128];   // 256B rows, swizzled
    __shared__ bf16 Vts[128 * 64];  // 128B rows, swizzled
    __shared__ bf16 Ps[64 * 64];    // 128B rows, swizzled
    int qb = blockIdx.x, h = blockIdx.y, kvh = h >> 2;
    int tid = threadIdx.x, wave = tid >> 6, lane = tid & 63;
    int lr = lane & 15, kgrp = lane >> 4;

    // staging source precompute: linear dest byte p -> swizzled source (row,col)
    int rowQ[4], colQ[4];  // 256B-row tiles (Q, K)
    int rowV[4], colV[4];  // 128B-row tiles (Vt)
#pragma unroll
    for (int j = 0; j < 4; j++) {
        int p = j * 4096 + wave * 1024 + lane * 16;
        int ps = p ^ (((p >> 8) & 7) << 4);
        rowQ[j] = ps >> 8; colQ[j] = ps & 255;
        int pv = p ^ (((p >> 7) & 7) << 4);
        rowV[j] = pv >> 7; colV[j] = pv & 127;
    }

    // stage Q (once)
#pragma unroll
    for (int j = 0; j < 4; j++)
        GLP16((const char*)qg + (size_t)(qb * 64 + rowQ[j]) * 4096 + h * 256 + colQ[j],
              (char*)Qs + j * 4096 + wave * 1024);
    __syncthreads();
    bf16x8 qf[4];
#pragma unroll
    for (int c = 0; c < 4; c++) {
        int b = (wave * 16 + lr) * 256 + c * 64 + kgrp * 16;
        qf[c] = *(const bf16x8*)((const char*)Qs + (b ^ (((b >> 8) & 7) << 4)));
    }
    f32x4 accO[8];
#pragma unroll
    for (int n = 0; n < 8; n++) accO[n] = (f32x4){0, 0, 0, 0};
    float lsum[4] = {0, 0, 0, 0};
    const float scl = 0.08838834764831845f;  // 1/sqrt(128)
    int ntiles = qb + 1;
    for (int kt = 0; kt < ntiles; kt++) {
        __syncthreads();
#pragma unroll
        for (int j = 0; j < 4; j++)
            GLP16((const char*)kgl + (size_t)(kt * 64 + rowQ[j]) * 1024 + kvh * 256 + colQ[j],
                  (char*)Ks + j * 4096 + wave * 1024);
#pragma unroll
        for (int j = 0; j < 4; j++)
            GLP16((const char*)vtg + (size_t)(kvh * 128 + rowV[j]) * 4096 + kt * 128 + colV[j],
                  (char*)Vts + j * 4096 + wave * 1024);
        __syncthreads();
        int qrow = qb * 64 + wave * 16 + kgrp * 4;
#pragma unroll
        for (int j = 0; j < 4; j++) {
            f32x4 s = {0, 0, 0, 0};
#pragma unroll
            for (int c = 0; c < 4; c++) {
                int b = (j * 16 + lr) * 256 + c * 64 + kgrp * 16;
                bf16x8 kf = *(const bf16x8*)((const char*)Ks + (b ^ (((b >> 8) & 7) << 4)));
                s = mfma16(qf[c], kf, s);
            }
            int key = kt * 64 + j * 16 + lr;
#pragma unroll
            for (int r = 0; r < 4; r++) {
                // p = exp(50*tanh(y)-50) = exp(-100/(e^{2y}+1)), y = s*scl/50
                float e2y = __expf(s[r] * (scl * 0.04f));
                float pv = (key <= qrow + r) ? __expf(-100.0f / (e2y + 1.0f)) : 0.0f;
                lsum[r] += pv;
                int wb = (wave * 16 + kgrp * 4 + r) * 128 + (j * 16 + lr) * 2;
                *(bf16*)((char*)Ps + (wb ^ (((wb >> 7) & 7) << 4))) = (bf16)pv;
            }
        }
        bf16x8 pf[2];
#pragma unroll
        for (int ks2 = 0; ks2 < 2; ks2++) {
            int b = (wave * 16 + lr) * 128 + ks2 * 64 + kgrp * 16;
            pf[ks2] = *(const bf16x8*)((const char*)Ps + (b ^ (((b >> 7) & 7) << 4)));
        }
#pragma unroll
        for (int n = 0; n < 8; n++)
#pragma unroll
            for (int ks2 = 0; ks2 < 2; ks2++) {
                int b = (n * 16 + lr) * 128 + ks2 * 64 + kgrp * 16;
                bf16x8 vf = *(const bf16x8*)((const char*)Vts + (b ^ (((b >> 7) & 7) << 4)));
                accO[n] = mfma16(pf[ks2], vf, accO[n]);
            }
    }
#pragma unroll
    for (int r = 0; r < 4; r++) {
        float t = lsum[r];
        t += __shfl_xor(t, 1); t += __shfl_xor(t, 2);
        t += __shfl_xor(t, 4); t += __shfl_xor(t, 8);
        lsum[r] = t;
    }
#pragma unroll
    for (int n = 0; n < 8; n++)
#pragma unroll
        for (int r = 0; r < 4; r++) {
            size_t row = qb * 64 + wave * 16 + kgrp * 4 + r;
            og[row * 2048 + h * 128 + n * 16 + lr] = (bf16)(accO[n][r] / lsum[r]);
        }
}

// --------------------------------------------------------------------------
extern "C" void kernel_launch(void* const* d_in, const int* in_sizes, int n_in,
                              void* d_out, int out_size, void* d_ws, size_t ws_size,
                              hipStream_t stream) {
    const float* x      = (const float*)d_in[0];
    const float* attn_w = (const float*)d_in[1];
    const float* mlp_w  = (const float*)d_in[2];
    const float* wq     = (const float*)d_in[3];
    const float* wk     = (const float*)d_in[4];
    const float* wv     = (const float*)d_in[5];
    const float* wo     = (const float*)d_in[6];
    const float* wgate  = (const float*)d_in[7];
    const float* wup    = (const float*)d_in[8];
    const float* wdown  = (const float*)d_in[9];
    float* out = (float*)d_out;
    char* ws = (char*)d_ws;

    const size_t MB = 1024 * 1024;
    bf16* W1  = (bf16*)(ws + 0);        // 32MB: wqT, later wgateT
    bf16* W2  = (bf16*)(ws + 32 * MB);  // 32MB: wkT, woT, wupT
    bf16* W3  = (bf16*)(ws + 64 * MB);  // 32MB: wvT, wdownT
    bf16* hb  = (bf16*)(ws + 96 * MB);  // 8MB: h, later h2
    bf16* qb  = (bf16*)(ws + 104 * MB); // 8MB
    bf16* kb  = (bf16*)(ws + 112 * MB); // 2MB
    bf16* vb  = (bf16*)(ws + 114 * MB); // 2MB
    bf16* ob  = (bf16*)(ws + 116 * MB); // 8MB
    float* x2 = (float*)(ws + 124 * MB);// 16MB
    bf16* gb  = (bf16*)(ws + 140 * MB); // 32MB (gate, then silu(g)*u in place)
    bf16* vt  = (bf16*)(ws + 0);        // 2MB, aliases W1 (wqT dead by then)

    dim3 cb(32, 8);

    // 1. attn RMSNorm
    k_rmsnorm<<<2048, 256, 0, stream>>>(x, attn_w, hb);
    // 2. convert QKV weights (transposed bf16)
    k_convT<<<dim3(64, 64), cb, 0, stream>>>(wq, W1, 2048, 2048);
    k_convT<<<dim3(64, 16), cb, 0, stream>>>(wk, W2, 2048, 512);
    k_convT<<<dim3(64, 16), cb, 0, stream>>>(wv, W3, 2048, 512);
    // 3. QKV projections
    k_gemm<0><<<dim3(16, 16), 256, 0, stream>>>(hb, W1, qb, nullptr, 2048, 2048, 2048);
    k_gemm<0><<<dim3(4, 16), 256, 0, stream>>>(hb, W2, kb, nullptr, 2048, 512, 2048);
    k_gemm<0><<<dim3(4, 16), 256, 0, stream>>>(hb, W3, vb, nullptr, 2048, 512, 2048);
    // 4. V transpose (vb[2048][512] -> vt[512][2048]); W1/wqT is dead now
    k_transpose<<<dim3(64, 16), 256, 0, stream>>>(vb, vt, 2048, 512);
    // 5. RoPE + qk-norm (in place), q has 16 heads, k has 4
    k_rope<<<dim3(2048, 20), 64, 0, stream>>>(qb, kb);
    // 6. attention
    k_attn<<<dim3(32, 16), 256, 0, stream>>>(qb, kb, vt, ob);
    // 7. O projection + residual -> x2 (fp32)
    k_convT<<<dim3(64, 64), cb, 0, stream>>>(wo, W2, 2048, 2048);
    k_gemm<1><<<dim3(16, 16), 256, 0, stream>>>(ob, W2, x2, x, 2048, 2048, 2048);
    // 8. MLP RMSNorm
    k_rmsnorm<<<2048, 256, 0, stream>>>(x2, mlp_w, hb);
    // 9. gate GEMM
    k_convT<<<dim3(64, 256), cb, 0, stream>>>(wgate, W1, 2048, 8192);
    k_gemm<0><<<dim3(64, 16), 256, 0, stream>>>(hb, W1, gb, nullptr, 2048, 8192, 2048);
    // 10. up GEMM with silu(gate)*up epilogue (in place over gb)
    k_convT<<<dim3(64, 256), cb, 0, stream>>>(wup, W2, 2048, 8192);
    k_gemm<2><<<dim3(64, 16), 256, 0, stream>>>(hb, W2, gb, gb, 2048, 8192, 2048);
    // 11. down GEMM + residual -> out (fp32)
    k_convT<<<dim3(256, 64), cb, 0, stream>>>(wdown, W3, 8192, 2048);
    k_gemm<1><<<dim3(16, 16), 256, 0, stream>>>(gb, W3, out, x2, 2048, 2048, 8192);
}

// Round 3
// 608.317 us; speedup vs baseline: 1.4944x; 1.2668x over previous
//
#include <hip/hip_runtime.h>

typedef __bf16 bf16;
typedef __bf16 bf16x8 __attribute__((ext_vector_type(8)));
typedef float f32x4 __attribute__((ext_vector_type(4)));

#define GLP16(gp, lp) __builtin_amdgcn_global_load_lds( \
    (const __attribute__((address_space(1))) void*)(gp), \
    (__attribute__((address_space(3))) void*)(lp), 16, 0, 0)

__device__ __forceinline__ f32x4 mfma16(bf16x8 a, bf16x8 b, f32x4 c) {
    return __builtin_amdgcn_mfma_f32_16x16x32_bf16(a, b, c, 0, 0, 0);
}

// ---------------- RMSNorm: fp32 in -> bf16 out, row = 2048 ----------------
__global__ __launch_bounds__(256) void k_rmsnorm(const float* __restrict__ x,
        const float* __restrict__ w, bf16* __restrict__ out) {
    const int H = 2048;
    size_t row = blockIdx.x;
    const float* xr = x + row * H;
    int base = threadIdx.x * 8;
    float4 a = *(const float4*)(xr + base);
    float4 b = *(const float4*)(xr + base + 4);
    float ss = a.x*a.x + a.y*a.y + a.z*a.z + a.w*a.w
             + b.x*b.x + b.y*b.y + b.z*b.z + b.w*b.w;
#pragma unroll
    for (int m = 32; m > 0; m >>= 1) ss += __shfl_xor(ss, m);
    __shared__ float red[4];
    if ((threadIdx.x & 63) == 0) red[threadIdx.x >> 6] = ss;
    __syncthreads();
    float tot = red[0] + red[1] + red[2] + red[3];
    float rs = rsqrtf(tot * (1.0f / H) + 1e-5f);
    float4 wa = *(const float4*)(w + base);
    float4 wb = *(const float4*)(w + base + 4);
    bf16x8 ov;
    ov[0] = (bf16)(a.x * rs * wa.x); ov[1] = (bf16)(a.y * rs * wa.y);
    ov[2] = (bf16)(a.z * rs * wa.z); ov[3] = (bf16)(a.w * rs * wa.w);
    ov[4] = (bf16)(b.x * rs * wb.x); ov[5] = (bf16)(b.y * rs * wb.y);
    ov[6] = (bf16)(b.z * rs * wb.z); ov[7] = (bf16)(b.w * rs * wb.w);
    *(bf16x8*)(out + row * H + base) = ov;
}

// ------- convert + transpose: W (K x N fp32) -> Wt (N x K bf16) -----------
__global__ __launch_bounds__(256) void k_convT(const float* __restrict__ W,
        bf16* __restrict__ Wt, int K, int N) {
    __shared__ float t[32][33];
    int k0 = blockIdx.x * 32, n0 = blockIdx.y * 32;
    int tx = threadIdx.x, ty = threadIdx.y;
#pragma unroll
    for (int i = 0; i < 4; i++)
        t[ty + i * 8][tx] = W[(size_t)(k0 + ty + i * 8) * N + n0 + tx];
    __syncthreads();
#pragma unroll
    for (int i = 0; i < 4; i++)
        Wt[(size_t)(n0 + ty + i * 8) * K + k0 + tx] = (bf16)t[tx][ty + i * 8];
}

// ------- bf16 transpose: in (R x C) -> out (C x R) ------------------------
__global__ __launch_bounds__(256) void k_transpose(const bf16* __restrict__ in,
        bf16* __restrict__ out, int R, int C) {
    __shared__ bf16 t[32][33];
    int r0 = blockIdx.x * 32, c0 = blockIdx.y * 32;
    int tx = threadIdx.x & 31, ty = threadIdx.x >> 5;
#pragma unroll
    for (int i = 0; i < 4; i++)
        t[ty + i * 8][tx] = in[(size_t)(r0 + ty + i * 8) * C + c0 + tx];
    __syncthreads();
#pragma unroll
    for (int i = 0; i < 4; i++)
        out[(size_t)(c0 + ty + i * 8) * R + r0 + tx] = t[tx][ty + i * 8];
}

// ---------------- GEMM v1 (kept for QKV): 128x128 tile --------------------
template<int EPI>
__global__ __launch_bounds__(256) void k_gemm(const bf16* __restrict__ A,
        const bf16* __restrict__ Bt, void* __restrict__ outp,
        const void* __restrict__ aux, int M, int N, int K) {
    __shared__ bf16 As[128 * 32];
    __shared__ bf16 Bs[128 * 32];
    int tid = threadIdx.x;
    int wave = tid >> 6, lane = tid & 63;
    int lr = lane & 15, kg = lane >> 4;
    int bn = blockIdx.x, bm = blockIdx.y;
    int row0 = bm * 128, col0 = bn * 128;
    int wr = wave >> 1, wc = wave & 1;
    int ar = tid >> 2, ac = (tid & 3) * 8;
    const bf16* pa = A + (size_t)(row0 + ar) * K + ac;
    const bf16* pb = Bt + (size_t)(col0 + ar) * K + ac;
    char* lA = (char*)As + wave * 1024;
    char* lB = (char*)Bs + wave * 1024;
    f32x4 acc[4][4];
#pragma unroll
    for (int i = 0; i < 4; i++)
#pragma unroll
        for (int j = 0; j < 4; j++) acc[i][j] = (f32x4){0, 0, 0, 0};

    for (int k0 = 0; k0 < K; k0 += 32) {
        __syncthreads();
        GLP16(pa, lA);
        GLP16(pa + (size_t)64 * K, lA + 4096);
        GLP16(pb, lB);
        GLP16(pb + (size_t)64 * K, lB + 4096);
        pa += 32; pb += 32;
        __syncthreads();
        bf16x8 av[4], bv[4];
#pragma unroll
        for (int i = 0; i < 4; i++)
            av[i] = *(const bf16x8*)(As + (wr * 64 + i * 16 + lr) * 32 + kg * 8);
#pragma unroll
        for (int j = 0; j < 4; j++)
            bv[j] = *(const bf16x8*)(Bs + (wc * 64 + j * 16 + lr) * 32 + kg * 8);
#pragma unroll
        for (int i = 0; i < 4; i++)
#pragma unroll
            for (int j = 0; j < 4; j++)
                acc[i][j] = mfma16(av[i], bv[j], acc[i][j]);
    }
#pragma unroll
    for (int i = 0; i < 4; i++)
#pragma unroll
        for (int j = 0; j < 4; j++)
#pragma unroll
            for (int r = 0; r < 4; r++) {
                size_t row = row0 + wr * 64 + i * 16 + kg * 4 + r;
                size_t col = col0 + wc * 64 + j * 16 + lr;
                size_t idx = row * N + col;
                float vv = acc[i][j][r];
                if (EPI == 0) {
                    ((bf16*)outp)[idx] = (bf16)vv;
                } else if (EPI == 1) {
                    ((float*)outp)[idx] = ((const float*)aux)[idx] + vv;
                } else {
                    float g = (float)((const bf16*)aux)[idx];
                    float sg = g / (1.0f + __expf(-g));
                    ((bf16*)outp)[idx] = (bf16)(sg * vv);
                }
            }
}

// ---------------- GEMM v2: deep-pipelined 256x128, counted vmcnt ----------
// BM=256, BN=128, BK=64. 8 waves (4 M x 2 N), per-wave 64x64 output.
// LDS (dynamic 112KB): A: 2 bufs x 32KB @0 ; B: 3 bufs x 16KB @64KB.
// Schedule per tile t: issue A(t+1) (4 sets), B(t+2) (2 sets); compute t;
// s_waitcnt vmcnt(2) (B(t+2) may stay in flight); raw s_barrier.
// All tiles 128B rows, XOR-swizzled byte^=((row&7)<<4); GLP dest linear,
// global source pre-swizzled with the same involution (rule 21).
// EPI: 0 = bf16 store, 2 = silu(aux)*acc -> bf16, 3 = fp32 partial (split-K)
template<int EPI>
__global__ __launch_bounds__(512) void k_gemm2(const bf16* __restrict__ A,
        const bf16* __restrict__ Bt, void* __restrict__ outp,
        const void* __restrict__ aux, int M, int N, int K, int ksplit) {
    extern __shared__ char lds[];
    const int tid = threadIdx.x, wave = tid >> 6, lane = tid & 63;
    const int lr = lane & 15, kg = lane >> 4;
    const int wm = wave >> 1, wn = wave & 1;
    const int bn = blockIdx.x, bm = blockIdx.y, split = blockIdx.z;
    const int row0 = bm * 256, col0 = bn * 128;
    const int kbeg = split * ksplit;
    const int NT = ksplit >> 6;
    const size_t K2 = (size_t)K * 2;

    // staging source offsets: dest byte d -> source pos d ^ (((d>>7)&7)<<4)
    size_t offA[4];
#pragma unroll
    for (int s = 0; s < 4; s++) {
        int d = s * 8192 + tid * 16;
        int ps = d ^ (((d >> 7) & 7) << 4);
        offA[s] = (size_t)(ps >> 7) * K2 + (ps & 127);
    }
    const char* Abase = (const char*)(A + (size_t)row0 * K + kbeg);
    const char* Bbase = (const char*)(Bt + (size_t)col0 * K + kbeg);

    auto stageA = [&](int t) {
        const char* src = Abase + (size_t)t * 128;
        char* dst = lds + ((t & 1) * 32768) + wave * 1024;
#pragma unroll
        for (int s = 0; s < 4; s++)
            GLP16(src + offA[s], dst + s * 8192);
    };
    auto stageB = [&](int t, int bidx) {
        const char* src = Bbase + (size_t)t * 128;
        char* dst = lds + 65536 + bidx * 16384 + wave * 1024;
#pragma unroll
        for (int s = 0; s < 2; s++)
            GLP16(src + offA[s], dst + s * 8192);
    };

    f32x4 acc[4][4];
#pragma unroll
    for (int m = 0; m < 4; m++)
#pragma unroll
        for (int n = 0; n < 4; n++) acc[m][n] = (f32x4){0, 0, 0, 0};

    // prologue: A(0), B(0), B(1) -> wait all but B(1)'s 2 sets
    stageA(0); stageB(0, 0); stageB(1, 1);
    asm volatile("s_waitcnt vmcnt(2)" ::: "memory");
    __builtin_amdgcn_s_barrier();
    __builtin_amdgcn_sched_barrier(0);
    asm volatile("" ::: "memory");

    const int xorm = (lr & 7) << 4;
    int bcur = 0;
    for (int t = 0; t < NT; ++t) {
        if (t + 1 < NT) stageA(t + 1);
        int bnx = bcur + 2; if (bnx >= 3) bnx -= 3;
        if (t + 2 < NT) stageB(t + 2, bnx);
        const char* As_ = lds + ((t & 1) * 32768);
        const char* Bs_ = lds + 65536 + bcur * 16384;
#pragma unroll
        for (int h = 0; h < 2; ++h) {
            const int inner = (h * 64 + kg * 16) ^ xorm;
            bf16x8 av[4], bv[4];
#pragma unroll
            for (int m = 0; m < 4; m++)
                av[m] = *(const bf16x8*)(As_ + (wm * 64 + m * 16 + lr) * 128 + inner);
#pragma unroll
            for (int n = 0; n < 4; n++)
                bv[n] = *(const bf16x8*)(Bs_ + (wn * 64 + n * 16 + lr) * 128 + inner);
#pragma unroll
            for (int m = 0; m < 4; m++)
#pragma unroll
                for (int n = 0; n < 4; n++)
                    acc[m][n] = mfma16(av[m], bv[n], acc[m][n]);
        }
        if (t + 1 < NT) {
            if (t + 2 < NT) asm volatile("s_waitcnt vmcnt(2)" ::: "memory");
            else            asm volatile("s_waitcnt vmcnt(0)" ::: "memory");
            __builtin_amdgcn_s_barrier();
            __builtin_amdgcn_sched_barrier(0);
            asm volatile("" ::: "memory");
        }
        bcur++; if (bcur == 3) bcur = 0;
    }

#pragma unroll
    for (int m = 0; m < 4; m++)
#pragma unroll
        for (int n = 0; n < 4; n++)
#pragma unroll
            for (int r = 0; r < 4; r++) {
                size_t row = row0 + wm * 64 + m * 16 + kg * 4 + r;
                size_t col = col0 + wn * 64 + n * 16 + lr;
                size_t idx = row * N + col;
                float vv = acc[m][n][r];
                if (EPI == 0) {
                    ((bf16*)outp)[idx] = (bf16)vv;
                } else if (EPI == 2) {
                    float g = (float)((const bf16*)aux)[idx];
                    float sg = g / (1.0f + __expf(-g));
                    ((bf16*)outp)[idx] = (bf16)(sg * vv);
                } else {
                    ((float*)outp)[(size_t)split * M * N + idx] = vv;
                }
            }
}

// ---- reduce: out = resid + sum_s parts[s], fp32, vectorized float4 -------
__global__ __launch_bounds__(256) void k_reduce(const float* __restrict__ parts,
        const float* __restrict__ resid, float* __restrict__ out,
        int ns, size_t n4) {
    size_t i = (size_t)blockIdx.x * 256 + threadIdx.x;
    if (i >= n4) return;
    float4 acc = ((const float4*)resid)[i];
    for (int s = 0; s < ns; s++) {
        float4 p = ((const float4*)(parts + (size_t)s * n4 * 4))[i];
        acc.x += p.x; acc.y += p.y; acc.z += p.z; acc.w += p.w;
    }
    ((float4*)out)[i] = acc;
}

// ------------- RoPE + qk-norm, in-place on q (S x 2048) / k (S x 512) -----
__global__ __launch_bounds__(64) void k_rope(bf16* __restrict__ q,
        bf16* __restrict__ k) {
    int s = blockIdx.x, hid = blockIdx.y, lane = threadIdx.x;
    bf16* p;
    if (hid < 16) p = q + (size_t)s * 2048 + hid * 128;
    else          p = k + (size_t)s * 512 + (hid - 16) * 128;
    float x1 = (float)p[lane], x2 = (float)p[lane + 64];
    float f = powf(10000.0f, -(float)lane * (1.0f / 64.0f));
    float sn, cs;
    sincosf((float)s * f, &sn, &cs);
    float o1 = x1 * cs - x2 * sn;
    float o2 = x2 * cs + x1 * sn;
    float ss = o1 * o1 + o2 * o2;
#pragma unroll
    for (int m = 32; m > 0; m >>= 1) ss += __shfl_xor(ss, m);
    float rs = rsqrtf(ss * (1.0f / 128.0f) + 1e-5f);
    p[lane] = (bf16)(o1 * rs);
    p[lane + 64] = (bf16)(o2 * rs);
}

// ------------- flash attention, GQA 16q/4kv, causal, tanh softcap ---------
__global__ __launch_bounds__(256) void k_attn(const bf16* __restrict__ qg,
        const bf16* __restrict__ kgl, const bf16* __restrict__ vtg,
        bf16* __restrict__ og) {
    __shared__ bf16 Qs[64 * 128];   // 256B rows, swizzled
    __shared__ bf16 Ks[64 * 128];   // 256B rows, swizzled
    __shared__ bf16 Vts[128 * 64];  // 128B rows, swizzled
    __shared__ bf16 Ps[64 * 64];    // 128B rows, swizzled
    int qb = blockIdx.x, h = blockIdx.y, kvh = h >> 2;
    int tid = threadIdx.x, wave = tid >> 6, lane = tid & 63;
    int lr = lane & 15, kgrp = lane >> 4;

    int rowQ[4], colQ[4];
    int rowV[4], colV[4];
#pragma unroll
    for (int j = 0; j < 4; j++) {
        int p = j * 4096 + wave * 1024 + lane * 16;
        int ps = p ^ (((p >> 8) & 7) << 4);
        rowQ[j] = ps >> 8; colQ[j] = ps & 255;
        int pv = p ^ (((p >> 7) & 7) << 4);
        rowV[j] = pv >> 7; colV[j] = pv & 127;
    }

#pragma unroll
    for (int j = 0; j < 4; j++)
        GLP16((const char*)qg + (size_t)(qb * 64 + rowQ[j]) * 4096 + h * 256 + colQ[j],
              (char*)Qs + j * 4096 + wave * 1024);
    __syncthreads();
    bf16x8 qf[4];
#pragma unroll
    for (int c = 0; c < 4; c++) {
        int b = (wave * 16 + lr) * 256 + c * 64 + kgrp * 16;
        qf[c] = *(const bf16x8*)((const char*)Qs + (b ^ (((b >> 8) & 7) << 4)));
    }
    f32x4 accO[8];
#pragma unroll
    for (int n = 0; n < 8; n++) accO[n] = (f32x4){0, 0, 0, 0};
    float lsum[4] = {0, 0, 0, 0};
    const float scl = 0.08838834764831845f;  // 1/sqrt(128)
    int ntiles = qb + 1;
    for (int kt = 0; kt < ntiles; kt++) {
        __syncthreads();
#pragma unroll
        for (int j = 0; j < 4; j++)
            GLP16((const char*)kgl + (size_t)(kt * 64 + rowQ[j]) * 1024 + kvh * 256 + colQ[j],
                  (char*)Ks + j * 4096 + wave * 1024);
#pragma unroll
        for (int j = 0; j < 4; j++)
            GLP16((const char*)vtg + (size_t)(kvh * 128 + rowV[j]) * 4096 + kt * 128 + colV[j],
                  (char*)Vts + j * 4096 + wave * 1024);
        __syncthreads();
        int qrow = qb * 64 + wave * 16 + kgrp * 4;
#pragma unroll
        for (int j = 0; j < 4; j++) {
            f32x4 s = {0, 0, 0, 0};
#pragma unroll
            for (int c = 0; c < 4; c++) {
                int b = (j * 16 + lr) * 256 + c * 64 + kgrp * 16;
                bf16x8 kf = *(const bf16x8*)((const char*)Ks + (b ^ (((b >> 8) & 7) << 4)));
                s = mfma16(qf[c], kf, s);
            }
            int key = kt * 64 + j * 16 + lr;
#pragma unroll
            for (int r = 0; r < 4; r++) {
                float e2y = __expf(s[r] * (scl * 0.04f));
                float pv = (key <= qrow + r) ? __expf(-100.0f / (e2y + 1.0f)) : 0.0f;
                lsum[r] += pv;
                int wb = (wave * 16 + kgrp * 4 + r) * 128 + (j * 16 + lr) * 2;
                *(bf16*)((char*)Ps + (wb ^ (((wb >> 7) & 7) << 4))) = (bf16)pv;
            }
        }
        bf16x8 pf[2];
#pragma unroll
        for (int ks2 = 0; ks2 < 2; ks2++) {
            int b = (wave * 16 + lr) * 128 + ks2 * 64 + kgrp * 16;
            pf[ks2] = *(const bf16x8*)((const char*)Ps + (b ^ (((b >> 7) & 7) << 4)));
        }
#pragma unroll
        for (int n = 0; n < 8; n++)
#pragma unroll
            for (int ks2 = 0; ks2 < 2; ks2++) {
                int b = (n * 16 + lr) * 128 + ks2 * 64 + kgrp * 16;
                bf16x8 vf = *(const bf16x8*)((const char*)Vts + (b ^ (((b >> 7) & 7) << 4)));
                accO[n] = mfma16(pf[ks2], vf, accO[n]);
            }
    }
#pragma unroll
    for (int r = 0; r < 4; r++) {
        float t = lsum[r];
        t += __shfl_xor(t, 1); t += __shfl_xor(t, 2);
        t += __shfl_xor(t, 4); t += __shfl_xor(t, 8);
        lsum[r] = t;
    }
#pragma unroll
    for (int n = 0; n < 8; n++)
#pragma unroll
        for (int r = 0; r < 4; r++) {
            size_t row = qb * 64 + wave * 16 + kgrp * 4 + r;
            og[row * 2048 + h * 128 + n * 16 + lr] = (bf16)(accO[n][r] / lsum[r]);
        }
}

// --------------------------------------------------------------------------
extern "C" void kernel_launch(void* const* d_in, const int* in_sizes, int n_in,
                              void* d_out, int out_size, void* d_ws, size_t ws_size,
                              hipStream_t stream) {
    const float* x      = (const float*)d_in[0];
    const float* attn_w = (const float*)d_in[1];
    const float* mlp_w  = (const float*)d_in[2];
    const float* wq     = (const float*)d_in[3];
    const float* wk     = (const float*)d_in[4];
    const float* wv     = (const float*)d_in[5];
    const float* wo     = (const float*)d_in[6];
    const float* wgate  = (const float*)d_in[7];
    const float* wup    = (const float*)d_in[8];
    const float* wdown  = (const float*)d_in[9];
    float* out = (float*)d_out;
    char* ws = (char*)d_ws;

    const size_t MB = 1024 * 1024;
    bf16* W1  = (bf16*)(ws + 0);        // 32MB: wqT, later wgateT
    bf16* W2  = (bf16*)(ws + 32 * MB);  // 32MB: wkT, woT, wupT
    bf16* W3  = (bf16*)(ws + 64 * MB);  // 32MB: wvT, wdownT
    bf16* hb  = (bf16*)(ws + 96 * MB);  // 8MB: h, later h2
    bf16* qb  = (bf16*)(ws + 104 * MB); // 8MB
    bf16* kb  = (bf16*)(ws + 112 * MB); // 2MB
    bf16* vb  = (bf16*)(ws + 114 * MB); // 2MB
    bf16* ob  = (bf16*)(ws + 116 * MB); // 8MB
    float* x2 = (float*)(ws + 124 * MB);// 16MB
    bf16* gb  = (bf16*)(ws + 140 * MB); // 32MB (gate, then silu(g)*u in place)
    bf16* vt  = (bf16*)(ws + 0);        // 2MB, aliases W1 (wqT dead by then)
    float* parts = (float*)(ws + 0);    // split-K partials: O 32MB, down 64MB

    const int LDS2 = 114688;
    hipFuncSetAttribute((const void*)&k_gemm2<0>,
        hipFuncAttributeMaxDynamicSharedMemorySize, LDS2);
    hipFuncSetAttribute((const void*)&k_gemm2<2>,
        hipFuncAttributeMaxDynamicSharedMemorySize, LDS2);
    hipFuncSetAttribute((const void*)&k_gemm2<3>,
        hipFuncAttributeMaxDynamicSharedMemorySize, LDS2);

    dim3 cb(32, 8);
    const size_t n4 = (size_t)2048 * 2048 / 4;

    // 1. attn RMSNorm
    k_rmsnorm<<<2048, 256, 0, stream>>>(x, attn_w, hb);
    // 2. convert QKV weights (transposed bf16)
    k_convT<<<dim3(64, 64), cb, 0, stream>>>(wq, W1, 2048, 2048);
    k_convT<<<dim3(64, 16), cb, 0, stream>>>(wk, W2, 2048, 512);
    k_convT<<<dim3(64, 16), cb, 0, stream>>>(wv, W3, 2048, 512);
    // 3. QKV projections (v1 engine)
    k_gemm<0><<<dim3(16, 16), 256, 0, stream>>>(hb, W1, qb, nullptr, 2048, 2048, 2048);
    k_gemm<0><<<dim3(4, 16), 256, 0, stream>>>(hb, W2, kb, nullptr, 2048, 512, 2048);
    k_gemm<0><<<dim3(4, 16), 256, 0, stream>>>(hb, W3, vb, nullptr, 2048, 512, 2048);
    // 4. V transpose (vb[2048][512] -> vt[512][2048])
    k_transpose<<<dim3(64, 16), 256, 0, stream>>>(vb, vt, 2048, 512);
    // 5. RoPE + qk-norm (in place)
    k_rope<<<dim3(2048, 20), 64, 0, stream>>>(qb, kb);
    // 6. attention
    k_attn<<<dim3(32, 16), 256, 0, stream>>>(qb, kb, vt, ob);
    // 7. O projection, split-K=2 -> fp32 partials (aliases wqT, dead)
    k_convT<<<dim3(64, 64), cb, 0, stream>>>(wo, W2, 2048, 2048);
    k_gemm2<3><<<dim3(16, 8, 2), 512, LDS2, stream>>>(ob, W2, parts, nullptr,
                                                      2048, 2048, 2048, 1024);
    k_reduce<<<4096, 256, 0, stream>>>(parts, x, x2, 2, n4);
    // 8. MLP RMSNorm
    k_rmsnorm<<<2048, 256, 0, stream>>>(x2, mlp_w, hb);
    // 9. gate GEMM (v2)
    k_convT<<<dim3(64, 256), cb, 0, stream>>>(wgate, W1, 2048, 8192);
    k_gemm2<0><<<dim3(64, 8, 1), 512, LDS2, stream>>>(hb, W1, gb, nullptr,
                                                      2048, 8192, 2048, 2048);
    // 10. up GEMM with silu(gate)*up epilogue (in place over gb)
    k_convT<<<dim3(64, 256), cb, 0, stream>>>(wup, W2, 2048, 8192);
    k_gemm2<2><<<dim3(64, 8, 1), 512, LDS2, stream>>>(hb, W2, gb, gb,
                                                      2048, 8192, 2048, 2048);
    // 11. down GEMM, split-K=4 -> partials (alias wgateT+wupT, dead)
    k_convT<<<dim3(256, 64), cb, 0, stream>>>(wdown, W3, 8192, 2048);
    k_gemm2<3><<<dim3(16, 8, 4), 512, LDS2, stream>>>(gb, W3, parts, nullptr,
                                                      2048, 2048, 8192, 2048);
    k_reduce<<<4096, 256, 0, stream>>>(parts, x2, out, 4, n4);
}

// Round 4
// 487.221 us; speedup vs baseline: 1.8659x; 1.2485x over previous
//
#include <hip/hip_runtime.h>

typedef __bf16 bf16;
typedef __bf16 bf16x8 __attribute__((ext_vector_type(8)));
typedef float f32x4 __attribute__((ext_vector_type(4)));

#define GLP16(gp, lp) __builtin_amdgcn_global_load_lds( \
    (const __attribute__((address_space(1))) void*)(gp), \
    (__attribute__((address_space(3))) void*)(lp), 16, 0, 0)

__device__ __forceinline__ f32x4 mfma16(bf16x8 a, bf16x8 b, f32x4 c) {
    return __builtin_amdgcn_mfma_f32_16x16x32_bf16(a, b, c, 0, 0, 0);
}

// ---------------- RMSNorm: fp32 in -> bf16 out, row = 2048 ----------------
__global__ __launch_bounds__(256) void k_rmsnorm(const float* __restrict__ x,
        const float* __restrict__ w, bf16* __restrict__ out) {
    const int H = 2048;
    size_t row = blockIdx.x;
    const float* xr = x + row * H;
    int base = threadIdx.x * 8;
    float4 a = *(const float4*)(xr + base);
    float4 b = *(const float4*)(xr + base + 4);
    float ss = a.x*a.x + a.y*a.y + a.z*a.z + a.w*a.w
             + b.x*b.x + b.y*b.y + b.z*b.z + b.w*b.w;
#pragma unroll
    for (int m = 32; m > 0; m >>= 1) ss += __shfl_xor(ss, m);
    __shared__ float red[4];
    if ((threadIdx.x & 63) == 0) red[threadIdx.x >> 6] = ss;
    __syncthreads();
    float tot = red[0] + red[1] + red[2] + red[3];
    float rs = rsqrtf(tot * (1.0f / H) + 1e-5f);
    float4 wa = *(const float4*)(w + base);
    float4 wb = *(const float4*)(w + base + 4);
    bf16x8 ov;
    ov[0] = (bf16)(a.x * rs * wa.x); ov[1] = (bf16)(a.y * rs * wa.y);
    ov[2] = (bf16)(a.z * rs * wa.z); ov[3] = (bf16)(a.w * rs * wa.w);
    ov[4] = (bf16)(b.x * rs * wb.x); ov[5] = (bf16)(b.y * rs * wb.y);
    ov[6] = (bf16)(b.z * rs * wb.z); ov[7] = (bf16)(b.w * rs * wb.w);
    *(bf16x8*)(out + row * H + base) = ov;
}

// ------- convert + transpose: W (K x N fp32) -> Wt (N x K bf16) -----------
__global__ __launch_bounds__(256) void k_convT(const float* __restrict__ W,
        bf16* __restrict__ Wt, int K, int N) {
    __shared__ float t[32][33];
    int k0 = blockIdx.x * 32, n0 = blockIdx.y * 32;
    int tx = threadIdx.x, ty = threadIdx.y;
#pragma unroll
    for (int i = 0; i < 4; i++)
        t[ty + i * 8][tx] = W[(size_t)(k0 + ty + i * 8) * N + n0 + tx];
    __syncthreads();
#pragma unroll
    for (int i = 0; i < 4; i++)
        Wt[(size_t)(n0 + ty + i * 8) * K + k0 + tx] = (bf16)t[tx][ty + i * 8];
}

// ------- bf16 transpose: in (R x C) -> out (C x R) ------------------------
__global__ __launch_bounds__(256) void k_transpose(const bf16* __restrict__ in,
        bf16* __restrict__ out, int R, int C) {
    __shared__ bf16 t[32][33];
    int r0 = blockIdx.x * 32, c0 = blockIdx.y * 32;
    int tx = threadIdx.x & 31, ty = threadIdx.x >> 5;
#pragma unroll
    for (int i = 0; i < 4; i++)
        t[ty + i * 8][tx] = in[(size_t)(r0 + ty + i * 8) * C + c0 + tx];
    __syncthreads();
#pragma unroll
    for (int i = 0; i < 4; i++)
        out[(size_t)(c0 + ty + i * 8) * R + r0 + tx] = t[tx][ty + i * 8];
}

// ---------------- GEMM v2: deep-pipelined 256x128, counted vmcnt ----------
// BM=256, BN=128, BK=64. 8 waves (4 M x 2 N), per-wave 64x64 output.
// LDS (dynamic 112KB): A: 2 bufs x 32KB @0 ; B: 3 bufs x 16KB @64KB.
// EPI: 0 = bf16 store, 2 = silu(aux)*acc -> bf16, 3 = fp32 partial (split-K),
//      4 = QKV scatter (outp=qb; kb=qb+4Mi elem; vb=kb+1Mi elem)
template<int EPI>
__global__ __launch_bounds__(512) void k_gemm2(const bf16* __restrict__ A,
        const bf16* __restrict__ Bt, void* __restrict__ outp,
        const void* __restrict__ aux, int M, int N, int K, int ksplit) {
    extern __shared__ char lds[];
    const int tid = threadIdx.x, wave = tid >> 6, lane = tid & 63;
    const int lr = lane & 15, kg = lane >> 4;
    const int wm = wave >> 1, wn = wave & 1;
    const int bn = blockIdx.x, bm = blockIdx.y, split = blockIdx.z;
    const int row0 = bm * 256, col0 = bn * 128;
    const int kbeg = split * ksplit;
    const int NT = ksplit >> 6;
    const size_t K2 = (size_t)K * 2;

    size_t offA[4];
#pragma unroll
    for (int s = 0; s < 4; s++) {
        int d = s * 8192 + tid * 16;
        int ps = d ^ (((d >> 7) & 7) << 4);
        offA[s] = (size_t)(ps >> 7) * K2 + (ps & 127);
    }
    const char* Abase = (const char*)(A + (size_t)row0 * K + kbeg);
    const char* Bbase = (const char*)(Bt + (size_t)col0 * K + kbeg);

    auto stageA = [&](int t) {
        const char* src = Abase + (size_t)t * 128;
        char* dst = lds + ((t & 1) * 32768) + wave * 1024;
#pragma unroll
        for (int s = 0; s < 4; s++)
            GLP16(src + offA[s], dst + s * 8192);
    };
    auto stageB = [&](int t, int bidx) {
        const char* src = Bbase + (size_t)t * 128;
        char* dst = lds + 65536 + bidx * 16384 + wave * 1024;
#pragma unroll
        for (int s = 0; s < 2; s++)
            GLP16(src + offA[s], dst + s * 8192);
    };

    f32x4 acc[4][4];
#pragma unroll
    for (int m = 0; m < 4; m++)
#pragma unroll
        for (int n = 0; n < 4; n++) acc[m][n] = (f32x4){0, 0, 0, 0};

    stageA(0); stageB(0, 0); stageB(1, 1);
    asm volatile("s_waitcnt vmcnt(2)" ::: "memory");
    __builtin_amdgcn_s_barrier();
    __builtin_amdgcn_sched_barrier(0);
    asm volatile("" ::: "memory");

    const int xorm = (lr & 7) << 4;
    int bcur = 0;
    for (int t = 0; t < NT; ++t) {
        if (t + 1 < NT) stageA(t + 1);
        int bnx = bcur + 2; if (bnx >= 3) bnx -= 3;
        if (t + 2 < NT) stageB(t + 2, bnx);
        const char* As_ = lds + ((t & 1) * 32768);
        const char* Bs_ = lds + 65536 + bcur * 16384;
#pragma unroll
        for (int h = 0; h < 2; ++h) {
            const int inner = (h * 64 + kg * 16) ^ xorm;
            bf16x8 av[4], bv[4];
#pragma unroll
            for (int m = 0; m < 4; m++)
                av[m] = *(const bf16x8*)(As_ + (wm * 64 + m * 16 + lr) * 128 + inner);
#pragma unroll
            for (int n = 0; n < 4; n++)
                bv[n] = *(const bf16x8*)(Bs_ + (wn * 64 + n * 16 + lr) * 128 + inner);
#pragma unroll
            for (int m = 0; m < 4; m++)
#pragma unroll
                for (int n = 0; n < 4; n++)
                    acc[m][n] = mfma16(av[m], bv[n], acc[m][n]);
        }
        if (t + 1 < NT) {
            if (t + 2 < NT) asm volatile("s_waitcnt vmcnt(2)" ::: "memory");
            else            asm volatile("s_waitcnt vmcnt(0)" ::: "memory");
            __builtin_amdgcn_s_barrier();
            __builtin_amdgcn_sched_barrier(0);
            asm volatile("" ::: "memory");
        }
        bcur++; if (bcur == 3) bcur = 0;
    }

#pragma unroll
    for (int m = 0; m < 4; m++)
#pragma unroll
        for (int n = 0; n < 4; n++)
#pragma unroll
            for (int r = 0; r < 4; r++) {
                size_t row = row0 + wm * 64 + m * 16 + kg * 4 + r;
                size_t col = col0 + wn * 64 + n * 16 + lr;
                size_t idx = row * N + col;
                float vv = acc[m][n][r];
                if (EPI == 0) {
                    ((bf16*)outp)[idx] = (bf16)vv;
                } else if (EPI == 2) {
                    float g = (float)((const bf16*)aux)[idx];
                    float sg = g / (1.0f + __expf(-g));
                    ((bf16*)outp)[idx] = (bf16)(sg * vv);
                } else if (EPI == 3) {
                    ((float*)outp)[(size_t)split * M * N + idx] = vv;
                } else {  // EPI == 4: QKV scatter
                    bf16* base = (bf16*)outp;
                    if (col < 2048)
                        base[row * 2048 + col] = (bf16)vv;
                    else if (col < 2560)
                        base[4194304 + row * 512 + (col - 2048)] = (bf16)vv;
                    else
                        base[5242880 + row * 512 + (col - 2560)] = (bf16)vv;
                }
            }
}

// ---- reduce: out = resid + sum_s parts[s], fp32, vectorized float4 -------
__global__ __launch_bounds__(256) void k_reduce(const float* __restrict__ parts,
        const float* __restrict__ resid, float* __restrict__ out,
        int ns, size_t n4) {
    size_t i = (size_t)blockIdx.x * 256 + threadIdx.x;
    if (i >= n4) return;
    float4 acc = ((const float4*)resid)[i];
    for (int s = 0; s < ns; s++) {
        float4 p = ((const float4*)(parts + (size_t)s * n4 * 4))[i];
        acc.x += p.x; acc.y += p.y; acc.z += p.z; acc.w += p.w;
    }
    ((float4*)out)[i] = acc;
}

// ---- fused: x2 = resid + sum parts; hb = rmsnorm(x2)*w  (row = 2048) -----
__global__ __launch_bounds__(256) void k_reduce_rms(const float* __restrict__ parts,
        const float* __restrict__ resid, const float* __restrict__ w,
        float* __restrict__ x2, bf16* __restrict__ hb, int ns) {
    const int H = 2048;
    size_t row = blockIdx.x;
    int base = threadIdx.x * 8;
    const float* rr = resid + row * H + base;
    float4 a = *(const float4*)rr;
    float4 b = *(const float4*)(rr + 4);
    for (int s = 0; s < ns; s++) {
        const float* pp = parts + (size_t)s * H * 2048 + row * H + base;
        float4 pa = *(const float4*)pp;
        float4 pb = *(const float4*)(pp + 4);
        a.x += pa.x; a.y += pa.y; a.z += pa.z; a.w += pa.w;
        b.x += pb.x; b.y += pb.y; b.z += pb.z; b.w += pb.w;
    }
    *(float4*)(x2 + row * H + base) = a;
    *(float4*)(x2 + row * H + base + 4) = b;
    float ss = a.x*a.x + a.y*a.y + a.z*a.z + a.w*a.w
             + b.x*b.x + b.y*b.y + b.z*b.z + b.w*b.w;
#pragma unroll
    for (int m = 32; m > 0; m >>= 1) ss += __shfl_xor(ss, m);
    __shared__ float red[4];
    if ((threadIdx.x & 63) == 0) red[threadIdx.x >> 6] = ss;
    __syncthreads();
    float tot = red[0] + red[1] + red[2] + red[3];
    float rs = rsqrtf(tot * (1.0f / H) + 1e-5f);
    float4 wa = *(const float4*)(w + base);
    float4 wb = *(const float4*)(w + base + 4);
    bf16x8 ov;
    ov[0] = (bf16)(a.x * rs * wa.x); ov[1] = (bf16)(a.y * rs * wa.y);
    ov[2] = (bf16)(a.z * rs * wa.z); ov[3] = (bf16)(a.w * rs * wa.w);
    ov[4] = (bf16)(b.x * rs * wb.x); ov[5] = (bf16)(b.y * rs * wb.y);
    ov[6] = (bf16)(b.z * rs * wb.z); ov[7] = (bf16)(b.w * rs * wb.w);
    *(bf16x8*)(hb + row * H + base) = ov;
}

// ------------- RoPE + qk-norm, in-place on q (S x 2048) / k (S x 512) -----
__global__ __launch_bounds__(64) void k_rope(bf16* __restrict__ q,
        bf16* __restrict__ k) {
    int s = blockIdx.x, hid = blockIdx.y, lane = threadIdx.x;
    bf16* p;
    if (hid < 16) p = q + (size_t)s * 2048 + hid * 128;
    else          p = k + (size_t)s * 512 + (hid - 16) * 128;
    float x1 = (float)p[lane], x2 = (float)p[lane + 64];
    float f = exp2f((float)lane * -0.2076205059304601f);  // 10000^(-lane/64)
    float sn, cs;
    sincosf((float)s * f, &sn, &cs);
    float o1 = x1 * cs - x2 * sn;
    float o2 = x2 * cs + x1 * sn;
    float ss = o1 * o1 + o2 * o2;
#pragma unroll
    for (int m = 32; m > 0; m >>= 1) ss += __shfl_xor(ss, m);
    float rs = rsqrtf(ss * (1.0f / 128.0f) + 1e-5f);
    p[lane] = (bf16)(o1 * rs);
    p[lane + 64] = (bf16)(o2 * rs);
}

// ------------- flash attention, GQA 16q/4kv, causal, tanh softcap ---------
// Balanced: block (pi,h) processes q-tiles pi and 31-pi => 33 K-tiles each.
// K/V double-buffered with counted vmcnt(8). Poly-tanh softcap (|y|<=0.227).
// Dynamic LDS 88KB: Q@0(16K), K@16K(2x16K), V@48K(2x16K), P@80K(8K).
__global__ __launch_bounds__(256) void k_attn(const bf16* __restrict__ qg,
        const bf16* __restrict__ kgl, const bf16* __restrict__ vtg,
        bf16* __restrict__ og) {
    extern __shared__ char alds[];
    int pi = blockIdx.x, h = blockIdx.y, kvh = h >> 2;
    int tid = threadIdx.x, wave = tid >> 6, lane = tid & 63;
    int lr = lane & 15, kgrp = lane >> 4;

    int rowQ[4], colQ[4], rowV[4], colV[4];
#pragma unroll
    for (int j = 0; j < 4; j++) {
        int p = j * 4096 + wave * 1024 + lane * 16;
        int ps = p ^ (((p >> 8) & 7) << 4);
        rowQ[j] = ps >> 8; colQ[j] = ps & 255;
        int pv = p ^ (((p >> 7) & 7) << 4);
        rowV[j] = pv >> 7; colV[j] = pv & 127;
    }

    const float C1 = 0.08838834764831845f / 50.0f;  // 1/(50*sqrt(128))
    const float L2E50 = 72.13475204444817f;         // 50*log2(e)

#pragma unroll 1
    for (int half = 0; half < 2; ++half) {
        int qt = half ? (31 - pi) : pi;
        int nt = qt + 1;

        // stage Q, K0/V0, (K1/V1)
#pragma unroll
        for (int j = 0; j < 4; j++)
            GLP16((const char*)qg + (size_t)(qt * 64 + rowQ[j]) * 4096 + h * 256 + colQ[j],
                  alds + j * 4096 + wave * 1024);
        for (int t = 0; t < 2 && t < nt; t++) {
#pragma unroll
            for (int j = 0; j < 4; j++)
                GLP16((const char*)kgl + (size_t)(t * 64 + rowQ[j]) * 1024 + kvh * 256 + colQ[j],
                      alds + 16384 + t * 16384 + j * 4096 + wave * 1024);
#pragma unroll
            for (int j = 0; j < 4; j++)
                GLP16((const char*)vtg + (size_t)(kvh * 128 + rowV[j]) * 4096 + t * 128 + colV[j],
                      alds + 49152 + t * 16384 + j * 4096 + wave * 1024);
        }
        if (nt > 1) asm volatile("s_waitcnt vmcnt(8)" ::: "memory");
        else        asm volatile("s_waitcnt vmcnt(0)" ::: "memory");
        __builtin_amdgcn_s_barrier();

        bf16x8 qf[4];
#pragma unroll
        for (int c = 0; c < 4; c++) {
            int b = (wave * 16 + lr) * 256 + c * 64 + kgrp * 16;
            qf[c] = *(const bf16x8*)(alds + (b ^ (((b >> 8) & 7) << 4)));
        }
        f32x4 accO[8];
#pragma unroll
        for (int n = 0; n < 8; n++) accO[n] = (f32x4){0, 0, 0, 0};
        float lsum[4] = {0, 0, 0, 0};
        int qrow = qt * 64 + wave * 16 + kgrp * 4;

        for (int kt = 0; kt < nt; kt++) {
            int buf = kt & 1;
            const char* Kb = alds + 16384 + buf * 16384;
            const char* Vb = alds + 49152 + buf * 16384;
            char* Pb = alds + 81920;
            // QK^T + softcap-softmax
#pragma unroll
            for (int j = 0; j < 4; j++) {
                f32x4 s = {0, 0, 0, 0};
#pragma unroll
                for (int c = 0; c < 4; c++) {
                    int b = (j * 16 + lr) * 256 + c * 64 + kgrp * 16;
                    bf16x8 kf = *(const bf16x8*)(Kb + (b ^ (((b >> 8) & 7) << 4)));
                    s = mfma16(qf[c], kf, s);
                }
                int key = kt * 64 + j * 16 + lr;
#pragma unroll
                for (int r = 0; r < 4; r++) {
                    float y = s[r] * C1;
                    float y2 = y * y;
                    float u = fmaf(y2, 0.13333333f, -0.33333333f);
                    u = fmaf(y2, u, 1.0f);
                    float t5 = y * u;                       // tanh(y)
                    float pe = fmaf(t5, L2E50, -L2E50);     // (50t-50)*log2e
                    float pv = (key <= qrow + r) ? exp2f(pe) : 0.0f;
                    lsum[r] += pv;
                    int wb = (wave * 16 + kgrp * 4 + r) * 128 + (j * 16 + lr) * 2;
                    *(bf16*)(Pb + (wb ^ (((wb >> 7) & 7) << 4))) = (bf16)pv;
                }
            }
            // PV
            bf16x8 pf[2];
#pragma unroll
            for (int ks2 = 0; ks2 < 2; ks2++) {
                int b = (wave * 16 + lr) * 128 + ks2 * 64 + kgrp * 16;
                pf[ks2] = *(const bf16x8*)(Pb + (b ^ (((b >> 7) & 7) << 4)));
            }
#pragma unroll
            for (int n = 0; n < 8; n++)
#pragma unroll
                for (int ks2 = 0; ks2 < 2; ks2++) {
                    int b = (n * 16 + lr) * 128 + ks2 * 64 + kgrp * 16;
                    bf16x8 vf = *(const bf16x8*)(Vb + (b ^ (((b >> 7) & 7) << 4)));
                    accO[n] = mfma16(pf[ks2], vf, accO[n]);
                }
            __builtin_amdgcn_s_barrier();
            bool more = (kt + 2 < nt);
            if (more) {
                int t = kt + 2;
#pragma unroll
                for (int j = 0; j < 4; j++)
                    GLP16((const char*)kgl + (size_t)(t * 64 + rowQ[j]) * 1024 + kvh * 256 + colQ[j],
                          alds + 16384 + buf * 16384 + j * 4096 + wave * 1024);
#pragma unroll
                for (int j = 0; j < 4; j++)
                    GLP16((const char*)vtg + (size_t)(kvh * 128 + rowV[j]) * 4096 + t * 128 + colV[j],
                          alds + 49152 + buf * 16384 + j * 4096 + wave * 1024);
            }
            if (kt + 1 < nt) {
                if (more) asm volatile("s_waitcnt vmcnt(8)" ::: "memory");
                else      asm volatile("s_waitcnt vmcnt(0)" ::: "memory");
                __builtin_amdgcn_s_barrier();
            }
        }
#pragma unroll
        for (int r = 0; r < 4; r++) {
            float t = lsum[r];
            t += __shfl_xor(t, 1); t += __shfl_xor(t, 2);
            t += __shfl_xor(t, 4); t += __shfl_xor(t, 8);
            lsum[r] = t;
        }
#pragma unroll
        for (int n = 0; n < 8; n++)
#pragma unroll
            for (int r = 0; r < 4; r++) {
                size_t row = qt * 64 + wave * 16 + kgrp * 4 + r;
                og[row * 2048 + h * 128 + n * 16 + lr] = (bf16)(accO[n][r] / lsum[r]);
            }
    }
}

// --------------------------------------------------------------------------
extern "C" void kernel_launch(void* const* d_in, const int* in_sizes, int n_in,
                              void* d_out, int out_size, void* d_ws, size_t ws_size,
                              hipStream_t stream) {
    const float* x      = (const float*)d_in[0];
    const float* attn_w = (const float*)d_in[1];
    const float* mlp_w  = (const float*)d_in[2];
    const float* wq     = (const float*)d_in[3];
    const float* wk     = (const float*)d_in[4];
    const float* wv     = (const float*)d_in[5];
    const float* wo     = (const float*)d_in[6];
    const float* wgate  = (const float*)d_in[7];
    const float* wup    = (const float*)d_in[8];
    const float* wdown  = (const float*)d_in[9];
    float* out = (float*)d_out;
    char* ws = (char*)d_ws;

    const size_t MB = 1024 * 1024;
    bf16* W1  = (bf16*)(ws + 0);        // wqkvT (12.6MB), later wgateT (32MB)
    bf16* W2  = (bf16*)(ws + 32 * MB);  // woT, wupT
    bf16* W3  = (bf16*)(ws + 64 * MB);  // wdownT
    bf16* hb  = (bf16*)(ws + 96 * MB);  // 8MB: h, later h2
    bf16* qb  = (bf16*)(ws + 104 * MB); // 8MB  (kb = qb+4Mi, vb = kb+1Mi elems)
    bf16* kb  = (bf16*)(ws + 112 * MB); // 2MB
    bf16* vb  = (bf16*)(ws + 114 * MB); // 2MB
    bf16* ob  = (bf16*)(ws + 116 * MB); // 8MB
    float* x2 = (float*)(ws + 124 * MB);// 16MB
    bf16* gb  = (bf16*)(ws + 140 * MB); // 32MB (gate, then silu(g)*u in place)
    bf16* vt  = (bf16*)(ws + 0);        // 2MB, aliases W1 (wqkvT dead by then)
    float* parts = (float*)(ws + 0);    // split-K partials: O 32MB, down 64MB

    const int LDS2 = 114688;
    hipFuncSetAttribute((const void*)&k_gemm2<0>,
        hipFuncAttributeMaxDynamicSharedMemorySize, LDS2);
    hipFuncSetAttribute((const void*)&k_gemm2<2>,
        hipFuncAttributeMaxDynamicSharedMemorySize, LDS2);
    hipFuncSetAttribute((const void*)&k_gemm2<3>,
        hipFuncAttributeMaxDynamicSharedMemorySize, LDS2);
    hipFuncSetAttribute((const void*)&k_gemm2<4>,
        hipFuncAttributeMaxDynamicSharedMemorySize, LDS2);
    const int LDSA = 90112;
    hipFuncSetAttribute((const void*)&k_attn,
        hipFuncAttributeMaxDynamicSharedMemorySize, LDSA);

    dim3 cb(32, 8);
    const size_t n4 = (size_t)2048 * 2048 / 4;

    // 1. attn RMSNorm
    k_rmsnorm<<<2048, 256, 0, stream>>>(x, attn_w, hb);
    // 2. convert QKV weights into one [3072][2048] bf16 Bt
    k_convT<<<dim3(64, 64), cb, 0, stream>>>(wq, W1, 2048, 2048);
    k_convT<<<dim3(64, 16), cb, 0, stream>>>(wk, W1 + 4194304, 2048, 512);
    k_convT<<<dim3(64, 16), cb, 0, stream>>>(wv, W1 + 5242880, 2048, 512);
    // 3. fused QKV projection with scatter epilogue
    k_gemm2<4><<<dim3(24, 8, 1), 512, LDS2, stream>>>(hb, W1, qb, nullptr,
                                                      2048, 3072, 2048, 2048);
    // 4. V transpose (vb[2048][512] -> vt[512][2048]); wqkvT dead now
    k_transpose<<<dim3(64, 16), 256, 0, stream>>>(vb, vt, 2048, 512);
    // 5. RoPE + qk-norm (in place)
    k_rope<<<dim3(2048, 20), 64, 0, stream>>>(qb, kb);
    // 6. attention (balanced pairing)
    k_attn<<<dim3(16, 16), 256, LDSA, stream>>>(qb, kb, vt, ob);
    // 7. O projection, split-K=2 -> fp32 partials; then fused reduce+rmsnorm
    k_convT<<<dim3(64, 64), cb, 0, stream>>>(wo, W2, 2048, 2048);
    k_gemm2<3><<<dim3(16, 8, 2), 512, LDS2, stream>>>(ob, W2, parts, nullptr,
                                                      2048, 2048, 2048, 1024);
    k_reduce_rms<<<2048, 256, 0, stream>>>(parts, x, mlp_w, x2, hb, 2);
    // 8. gate GEMM
    k_convT<<<dim3(64, 256), cb, 0, stream>>>(wgate, W1, 2048, 8192);
    k_gemm2<0><<<dim3(64, 8, 1), 512, LDS2, stream>>>(hb, W1, gb, nullptr,
                                                      2048, 8192, 2048, 2048);
    // 9. up GEMM with silu(gate)*up epilogue (in place over gb)
    k_convT<<<dim3(64, 256), cb, 0, stream>>>(wup, W2, 2048, 8192);
    k_gemm2<2><<<dim3(64, 8, 1), 512, LDS2, stream>>>(hb, W2, gb, gb,
                                                      2048, 8192, 2048, 2048);
    // 10. down GEMM, split-K=4 -> partials; reduce + residual -> out
    k_convT<<<dim3(256, 64), cb, 0, stream>>>(wdown, W3, 8192, 2048);
    k_gemm2<3><<<dim3(16, 8, 4), 512, LDS2, stream>>>(gb, W3, parts, nullptr,
                                                      2048, 2048, 8192, 2048);
    k_reduce<<<4096, 256, 0, stream>>>(parts, x2, out, 4, n4);
}